// Round 1
// baseline (426.343 us; speedup 1.0000x reference)
//
#include <hip/hip_runtime.h>
#include <math.h>

#define DD   256
#define BB   1024
#define NEGN 64
#define S1N  25
#define S2N  10
#define OUTN 128

// out[g*DD+t] = mean_s feat[row(g,s)*DD + t]; row = idx ? idx[g*fan+s] : g*fan+s
__global__ void gather_mean_k(const float* __restrict__ feat, const int* __restrict__ idx,
                              float* __restrict__ out, int fan) {
    int g = blockIdx.x;
    int t = threadIdx.x;
    float acc = 0.f;
    for (int s = 0; s < fan; ++s) {
        int row = idx ? idx[g * fan + s] : (g * fan + s);
        acc += feat[(long long)row * DD + t];
    }
    out[(long long)g * DD + t] = acc * (1.0f / fan);
}

// y[row][t<128 ? self : neigh] = act( dot(x, W[:,j]) ), K=256, R rows per block
template <int R>
__global__ void sage_layer_k(const float* __restrict__ xsrc, const int* __restrict__ idx,
                             const float* __restrict__ xneigh,
                             const float* __restrict__ Ws, const float* __restrict__ Wn,
                             float* __restrict__ out, int rows, int do_relu) {
    __shared__ float xsS[R][DD];
    __shared__ float xnS[R][DD];
    int r0 = blockIdx.x * R;
    int t = threadIdx.x;
    for (int r = 0; r < R; ++r) {
        int row = r0 + r;
        if (row < rows) {
            int src = idx ? idx[row] : row;
            xsS[r][t] = xsrc[(long long)src * DD + t];
            xnS[r][t] = xneigh[(long long)row * DD + t];
        } else {
            xsS[r][t] = 0.f; xnS[r][t] = 0.f;
        }
    }
    __syncthreads();
    const float* W = (t < OUTN) ? Ws : Wn;
    const float (*X)[DD] = (t < OUTN) ? xsS : xnS;
    int j = t & (OUTN - 1);
    float acc[R];
    for (int r = 0; r < R; ++r) acc[r] = 0.f;
#pragma unroll 8
    for (int k = 0; k < DD; ++k) {
        float w = W[k * OUTN + j];
        for (int r = 0; r < R; ++r) acc[r] = fmaf(X[r][k], w, acc[r]);
    }
    for (int r = 0; r < R; ++r) {
        int row = r0 + r;
        if (row < rows) {
            float v = acc[r];
            if (do_relu) v = fmaxf(v, 0.f);
            out[(long long)row * (2 * OUTN) + t] = v;
        }
    }
}

// final layer (no act) + row L2-normalize
__global__ void sage_final_k(const float* __restrict__ g0, const float* __restrict__ mg1,
                             const float* __restrict__ Ws, const float* __restrict__ Wn,
                             float* __restrict__ out) {
    __shared__ float xsS[DD], xnS[DD], red[256];
    int row = blockIdx.x, t = threadIdx.x;
    xsS[t] = g0[(long long)row * DD + t];
    xnS[t] = mg1[(long long)row * DD + t];
    __syncthreads();
    const float* W = (t < OUTN) ? Ws : Wn;
    const float* X = (t < OUTN) ? xsS : xnS;
    int j = t & (OUTN - 1);
    float acc = 0.f;
#pragma unroll 8
    for (int k = 0; k < DD; ++k) acc = fmaf(X[k], W[k * OUTN + j], acc);
    red[t] = acc * acc;
    __syncthreads();
    for (int s = 128; s > 0; s >>= 1) { if (t < s) red[t] += red[t + s]; __syncthreads(); }
    float nrm = fmaxf(sqrtf(red[0]), 1e-12f);
    out[(long long)row * DD + t] = acc / nrm;
}

// per-b: aff[b] = dot(u1[b],u2[b]); neg[b][j] = dot(u1[b], un[j])
__global__ void aff_neg_k(const float* __restrict__ u1, const float* __restrict__ u2,
                          const float* __restrict__ un, float* __restrict__ aff,
                          float* __restrict__ neg) {
    __shared__ float u1s[DD], red[256];
    int b = blockIdx.x, t = threadIdx.x;
    float a = u1[(long long)b * DD + t];
    u1s[t] = a;
    red[t] = a * u2[(long long)b * DD + t];
    __syncthreads();
    for (int s = 128; s > 0; s >>= 1) { if (t < s) red[t] += red[t + s]; __syncthreads(); }
    if (t == 0) aff[b] = red[0];
    // 4 threads per neg sample j
    int j = t >> 2, q = t & 3;
    float acc = 0.f;
    int k0 = q * 64;
    for (int k = k0; k < k0 + 64; ++k) acc += u1s[k] * un[j * DD + k];
    acc += __shfl_down(acc, 2, 64);
    acc += __shfl_down(acc, 1, 64);
    if (q == 0) neg[(long long)b * NEGN + j] = acc;
}

__device__ __forceinline__ float softplus_f(float x) {
    return fmaxf(x, 0.f) + log1pf(expf(-fabsf(x)));
}

__global__ void loss_k(const float* __restrict__ aff, const float* __restrict__ neg,
                       float* __restrict__ loss) {
    __shared__ float red[256];
    int t = threadIdx.x;
    float acc = 0.f;
    for (int i = t; i < BB; i += 256) acc += softplus_f(-aff[i]);
    for (int i = t; i < BB * NEGN; i += 256) acc += softplus_f(neg[i]);
    red[t] = acc;
    __syncthreads();
    for (int s = 128; s > 0; s >>= 1) { if (t < s) red[t] += red[t + s]; __syncthreads(); }
    if (t == 0) loss[0] = red[0] / (float)BB;
}

static void encode(const float* feat, const float* Ws0, const float* Wn0,
                   const float* Ws1, const float* Wn1,
                   const int* i0, const int* i1, const int* i2, int bs,
                   float* meanH2, float* meanH1, float* g1, float* g0, float* mg1,
                   float* dst, hipStream_t stream) {
    gather_mean_k<<<bs * S2N, 256, 0, stream>>>(feat, i2, meanH2, S1N);
    gather_mean_k<<<bs, 256, 0, stream>>>(feat, i1, meanH1, S2N);
    sage_layer_k<4><<<(bs * S2N) / 4, 256, 0, stream>>>(feat, i1, meanH2, Ws0, Wn0, g1, bs * S2N, 1);
    sage_layer_k<4><<<bs / 4, 256, 0, stream>>>(feat, i0, meanH1, Ws0, Wn0, g0, bs, 1);
    gather_mean_k<<<bs, 256, 0, stream>>>(g1, nullptr, mg1, S2N);
    sage_final_k<<<bs, 256, 0, stream>>>(g0, mg1, Ws1, Wn1, dst);
}

extern "C" void kernel_launch(void* const* d_in, const int* in_sizes, int n_in,
                              void* d_out, int out_size, void* d_ws, size_t ws_size,
                              hipStream_t stream) {
    const float* feat = (const float*)d_in[0];
    const float* Ws0  = (const float*)d_in[1];
    const float* Wn0  = (const float*)d_in[2];
    const float* Ws1  = (const float*)d_in[3];
    const float* Wn1  = (const float*)d_in[4];
    const int* s1_0 = (const int*)d_in[5];
    const int* s1_1 = (const int*)d_in[6];
    const int* s1_2 = (const int*)d_in[7];
    const int* s2_0 = (const int*)d_in[8];
    const int* s2_1 = (const int*)d_in[9];
    const int* s2_2 = (const int*)d_in[10];
    const int* n_0  = (const int*)d_in[11];
    const int* n_1  = (const int*)d_in[12];
    const int* n_2  = (const int*)d_in[13];

    float* out = (float*)d_out;
    float* loss    = out;                      // [1]
    float* aff     = out + 1;                  // [BB]
    float* neg     = out + 1 + BB;             // [BB*NEGN]
    float* u1      = out + 1 + BB + BB * NEGN; // [BB*DD]

    float* ws = (float*)d_ws;
    size_t off = 0;
    float* meanH2 = ws + off; off += (size_t)BB * S2N * DD;   // 2.62M
    float* meanH1 = ws + off; off += (size_t)BB * DD;         // 262K
    float* g1buf  = ws + off; off += (size_t)BB * S2N * DD;   // 2.62M
    float* g0buf  = ws + off; off += (size_t)BB * DD;
    float* mg1    = ws + off; off += (size_t)BB * DD;
    float* u2     = ws + off; off += (size_t)BB * DD;
    float* un     = ws + off; off += (size_t)NEGN * DD;

    encode(feat, Ws0, Wn0, Ws1, Wn1, s1_0, s1_1, s1_2, BB,
           meanH2, meanH1, g1buf, g0buf, mg1, u1, stream);
    encode(feat, Ws0, Wn0, Ws1, Wn1, s2_0, s2_1, s2_2, BB,
           meanH2, meanH1, g1buf, g0buf, mg1, u2, stream);
    encode(feat, Ws0, Wn0, Ws1, Wn1, n_0, n_1, n_2, NEGN,
           meanH2, meanH1, g1buf, g0buf, mg1, un, stream);

    aff_neg_k<<<BB, 256, 0, stream>>>(u1, u2, un, aff, neg);
    loss_k<<<1, 256, 0, stream>>>(aff, neg, loss);
}

// Round 2
// 163.466 us; speedup vs baseline: 2.6081x; 2.6081x over previous
//
#include <hip/hip_runtime.h>
#include <math.h>

#define DD   256
#define BB   1024
#define NEGN 64
#define S1N  25
#define S2N  10
#define OUTN 128

struct Seg3 {
    const int* iself[3];
    const int* ineigh[3];
    float* out[3];
    int b0, b1;   // block counts of segment 0 and 1
};

struct SegF {
    const float* g0[3];
    const float* g1[3];
    float* out[3];
    int b0, b1;
};

// Fused: neigh-mean gather (FAN rows of feat) + self gather + SAGE layer0 (ReLU).
// R rows per block, 256 threads. Wave w stages rows [w*R/4, w*R/4+R/4).
template <int R, int FAN>
__global__ __launch_bounds__(256)
void layer0_fused_k(const float* __restrict__ feat, Seg3 a,
                    const float* __restrict__ Ws, const float* __restrict__ Wn) {
    __shared__ float xsS[R][DD];
    __shared__ float xnS[R][DD];
    int blk = blockIdx.x;
    int seg, base;
    if (blk < a.b0) { seg = 0; base = 0; }
    else if (blk < a.b0 + a.b1) { seg = 1; base = a.b0; }
    else { seg = 2; base = a.b0 + a.b1; }
    const int* iself  = a.iself[seg];
    const int* ineigh = a.ineigh[seg];
    float* out = a.out[seg];
    int r0 = (blk - base) * R;

    int wv = threadIdx.x >> 6;
    int c  = threadIdx.x & 63;

#pragma unroll
    for (int rr = 0; rr < R / 4; ++rr) {
        int r = wv * (R / 4) + rr;
        int row = r0 + r;
        int src = iself[row];
        *(float4*)&xsS[r][c * 4] = *(const float4*)(feat + (size_t)src * DD + c * 4);
        float4 acc = make_float4(0.f, 0.f, 0.f, 0.f);
        const int* ip = ineigh + (size_t)row * FAN;
#pragma unroll
        for (int s = 0; s < FAN; ++s) {
            int nr = ip[s];
            float4 x = *(const float4*)(feat + (size_t)nr * DD + c * 4);
            acc.x += x.x; acc.y += x.y; acc.z += x.z; acc.w += x.w;
        }
        const float inv = 1.0f / FAN;
        acc.x *= inv; acc.y *= inv; acc.z *= inv; acc.w *= inv;
        *(float4*)&xnS[r][c * 4] = acc;
    }
    __syncthreads();

    int j = threadIdx.x & (OUTN - 1);
    const float* Wj = ((threadIdx.x < OUTN) ? Ws : Wn) + j;
    const float (*X)[DD] = (threadIdx.x < OUTN) ? xsS : xnS;
    float acc[R];
#pragma unroll
    for (int r = 0; r < R; ++r) acc[r] = 0.f;
#pragma unroll 4
    for (int k4 = 0; k4 < DD; k4 += 4) {
        float w0 = Wj[(k4 + 0) * OUTN];
        float w1 = Wj[(k4 + 1) * OUTN];
        float w2 = Wj[(k4 + 2) * OUTN];
        float w3 = Wj[(k4 + 3) * OUTN];
#pragma unroll
        for (int r = 0; r < R; ++r) {
            float4 x = *(const float4*)&X[r][k4];
            acc[r] = fmaf(x.x, w0, acc[r]);
            acc[r] = fmaf(x.y, w1, acc[r]);
            acc[r] = fmaf(x.z, w2, acc[r]);
            acc[r] = fmaf(x.w, w3, acc[r]);
        }
    }
#pragma unroll
    for (int r = 0; r < R; ++r) {
        int row = r0 + r;
        out[(size_t)row * (2 * OUTN) + threadIdx.x] = fmaxf(acc[r], 0.f);
    }
}

// Fused: neigh-mean over FAN consecutive g1 rows + final layer (no act) + L2 norm.
// R must be 8 (norm reduction uses 8 groups of 32 threads).
template <int R, int FAN>
__global__ __launch_bounds__(256)
void final_fused_k(SegF a, const float* __restrict__ Ws, const float* __restrict__ Wn) {
    __shared__ float xsS[R][DD];
    __shared__ float xnS[R][DD];
    __shared__ float nrmS[R];
    int blk = blockIdx.x;
    int seg, base;
    if (blk < a.b0) { seg = 0; base = 0; }
    else if (blk < a.b0 + a.b1) { seg = 1; base = a.b0; }
    else { seg = 2; base = a.b0 + a.b1; }
    const float* g0 = a.g0[seg];
    const float* g1 = a.g1[seg];
    float* out = a.out[seg];
    int r0 = (blk - base) * R;

    int wv = threadIdx.x >> 6;
    int c  = threadIdx.x & 63;

#pragma unroll
    for (int rr = 0; rr < R / 4; ++rr) {
        int r = wv * (R / 4) + rr;
        int row = r0 + r;
        *(float4*)&xsS[r][c * 4] = *(const float4*)(g0 + (size_t)row * DD + c * 4);
        float4 acc = make_float4(0.f, 0.f, 0.f, 0.f);
#pragma unroll
        for (int s = 0; s < FAN; ++s) {
            float4 x = *(const float4*)(g1 + ((size_t)row * FAN + s) * DD + c * 4);
            acc.x += x.x; acc.y += x.y; acc.z += x.z; acc.w += x.w;
        }
        const float inv = 1.0f / FAN;
        acc.x *= inv; acc.y *= inv; acc.z *= inv; acc.w *= inv;
        *(float4*)&xnS[r][c * 4] = acc;
    }
    __syncthreads();

    int j = threadIdx.x & (OUTN - 1);
    const float* Wj = ((threadIdx.x < OUTN) ? Ws : Wn) + j;
    const float (*X)[DD] = (threadIdx.x < OUTN) ? xsS : xnS;
    float acc[R];
#pragma unroll
    for (int r = 0; r < R; ++r) acc[r] = 0.f;
#pragma unroll 4
    for (int k4 = 0; k4 < DD; k4 += 4) {
        float w0 = Wj[(k4 + 0) * OUTN];
        float w1 = Wj[(k4 + 1) * OUTN];
        float w2 = Wj[(k4 + 2) * OUTN];
        float w3 = Wj[(k4 + 3) * OUTN];
#pragma unroll
        for (int r = 0; r < R; ++r) {
            float4 x = *(const float4*)&X[r][k4];
            acc[r] = fmaf(x.x, w0, acc[r]);
            acc[r] = fmaf(x.y, w1, acc[r]);
            acc[r] = fmaf(x.z, w2, acc[r]);
            acc[r] = fmaf(x.w, w3, acc[r]);
        }
    }
    __syncthreads();                 // done reading xsS; reuse as sq scratch
    float* sq = &xsS[0][0];
#pragma unroll
    for (int r = 0; r < R; ++r) sq[r * DD + threadIdx.x] = acc[r] * acc[r];
    __syncthreads();
    {
        int g = threadIdx.x >> 5, l = threadIdx.x & 31;
        float s = 0.f;
#pragma unroll
        for (int i = 0; i < 8; ++i) s += sq[g * DD + l + 32 * i];
        s += __shfl_down(s, 16, 64);
        s += __shfl_down(s, 8, 64);
        s += __shfl_down(s, 4, 64);
        s += __shfl_down(s, 2, 64);
        s += __shfl_down(s, 1, 64);
        if (l == 0) nrmS[g] = fmaxf(sqrtf(s), 1e-12f);
    }
    __syncthreads();
#pragma unroll
    for (int r = 0; r < R; ++r) {
        int row = r0 + r;
        out[(size_t)row * DD + threadIdx.x] = acc[r] / nrmS[r];
    }
}

__device__ __forceinline__ float softplus_f(float x) {
    return fmaxf(x, 0.f) + log1pf(expf(-fabsf(x)));
}

// per-b: aff[b], neg[b][0..63], and partial loss contribution part[b]
__global__ __launch_bounds__(256)
void aff_neg_k(const float* __restrict__ u1, const float* __restrict__ u2,
               const float* __restrict__ un, float* __restrict__ aff,
               float* __restrict__ neg, float* __restrict__ part) {
    __shared__ float u1s[DD];
    __shared__ float red[256];
    int b = blockIdx.x, t = threadIdx.x;
    float av = u1[(size_t)b * DD + t];
    u1s[t] = av;
    red[t] = av * u2[(size_t)b * DD + t];
    __syncthreads();
    for (int s = 128; s > 0; s >>= 1) { if (t < s) red[t] += red[t + s]; __syncthreads(); }
    float affv = red[0];
    __syncthreads();
    if (t == 0) aff[b] = affv;

    int j = t >> 2, q = t & 3;
    float acc = 0.f;
    const float* up = un + (size_t)j * DD + q * 64;
    const float* us = u1s + q * 64;
#pragma unroll
    for (int i = 0; i < 16; ++i) {
        float4 x = *(const float4*)(up + 4 * i);
        float4 y = *(const float4*)(us + 4 * i);
        acc = fmaf(x.x, y.x, acc); acc = fmaf(x.y, y.y, acc);
        acc = fmaf(x.z, y.z, acc); acc = fmaf(x.w, y.w, acc);
    }
    acc += __shfl_down(acc, 2, 64);
    acc += __shfl_down(acc, 1, 64);
    float sp = 0.f;
    if (q == 0) {
        neg[(size_t)b * NEGN + j] = acc;
        sp = softplus_f(acc);
    }
    if (t == 0) sp += softplus_f(-affv);
    red[t] = sp;
    __syncthreads();
    for (int s = 128; s > 0; s >>= 1) { if (t < s) red[t] += red[t + s]; __syncthreads(); }
    if (t == 0) part[b] = red[0];
}

__global__ __launch_bounds__(256)
void loss_final_k(const float* __restrict__ part, float* __restrict__ loss) {
    __shared__ float red[256];
    int t = threadIdx.x;
    red[t] = part[t] + part[t + 256] + part[t + 512] + part[t + 768];
    __syncthreads();
    for (int s = 128; s > 0; s >>= 1) { if (t < s) red[t] += red[t + s]; __syncthreads(); }
    if (t == 0) loss[0] = red[0] / (float)BB;
}

extern "C" void kernel_launch(void* const* d_in, const int* in_sizes, int n_in,
                              void* d_out, int out_size, void* d_ws, size_t ws_size,
                              hipStream_t stream) {
    const float* feat = (const float*)d_in[0];
    const float* Ws0  = (const float*)d_in[1];
    const float* Wn0  = (const float*)d_in[2];
    const float* Ws1  = (const float*)d_in[3];
    const float* Wn1  = (const float*)d_in[4];
    const int* s1_0 = (const int*)d_in[5];
    const int* s1_1 = (const int*)d_in[6];
    const int* s1_2 = (const int*)d_in[7];
    const int* s2_0 = (const int*)d_in[8];
    const int* s2_1 = (const int*)d_in[9];
    const int* s2_2 = (const int*)d_in[10];
    const int* n_0  = (const int*)d_in[11];
    const int* n_1  = (const int*)d_in[12];
    const int* n_2  = (const int*)d_in[13];

    float* out  = (float*)d_out;
    float* loss = out;                      // [1]
    float* aff  = out + 1;                  // [BB]
    float* neg  = out + 1 + BB;             // [BB*NEGN]
    float* u1   = out + 1 + BB + BB * NEGN; // [BB*DD]

    float* ws = (float*)d_ws;
    size_t off = 0;
    float* g1a = ws + off; off += (size_t)BB * S2N * DD;    // 10240 rows
    float* g1b = ws + off; off += (size_t)BB * S2N * DD;
    float* g1n = ws + off; off += (size_t)NEGN * S2N * DD;  // 640 rows
    float* g0a = ws + off; off += (size_t)BB * DD;
    float* g0b = ws + off; off += (size_t)BB * DD;
    float* g0n = ws + off; off += (size_t)NEGN * DD;
    float* u2  = ws + off; off += (size_t)BB * DD;
    float* un  = ws + off; off += (size_t)NEGN * DD;
    float* part = ws + off; off += BB;

    constexpr int R = 8;

    // Stage 1: layer0 on hop-1 rows (self=i1, neigh=mean of 25 hop-2 feats)
    {
        Seg3 a;
        a.iself[0] = s1_1; a.iself[1] = s2_1; a.iself[2] = n_1;
        a.ineigh[0] = s1_2; a.ineigh[1] = s2_2; a.ineigh[2] = n_2;
        a.out[0] = g1a; a.out[1] = g1b; a.out[2] = g1n;
        a.b0 = (BB * S2N) / R; a.b1 = (BB * S2N) / R;
        int nb = a.b0 + a.b1 + (NEGN * S2N) / R;
        layer0_fused_k<R, S1N><<<nb, 256, 0, stream>>>(feat, a, Ws0, Wn0);
    }
    // Stage 2: layer0 on hop-0 rows (self=i0, neigh=mean of 10 hop-1 feats)
    {
        Seg3 a;
        a.iself[0] = s1_0; a.iself[1] = s2_0; a.iself[2] = n_0;
        a.ineigh[0] = s1_1; a.ineigh[1] = s2_1; a.ineigh[2] = n_1;
        a.out[0] = g0a; a.out[1] = g0b; a.out[2] = g0n;
        a.b0 = BB / R; a.b1 = BB / R;
        int nb = a.b0 + a.b1 + NEGN / R;
        layer0_fused_k<R, S2N><<<nb, 256, 0, stream>>>(feat, a, Ws0, Wn0);
    }
    // Stage 3: final layer (self=g0, neigh=mean of 10 g1 rows) + L2 norm
    {
        SegF a;
        a.g0[0] = g0a; a.g0[1] = g0b; a.g0[2] = g0n;
        a.g1[0] = g1a; a.g1[1] = g1b; a.g1[2] = g1n;
        a.out[0] = u1; a.out[1] = u2; a.out[2] = un;
        a.b0 = BB / R; a.b1 = BB / R;
        int nb = a.b0 + a.b1 + NEGN / R;
        final_fused_k<R, S2N><<<nb, 256, 0, stream>>>(a, Ws1, Wn1);
    }

    aff_neg_k<<<BB, 256, 0, stream>>>(u1, u2, un, aff, neg, part);
    loss_final_k<<<1, 256, 0, stream>>>(part, loss);
}

// Round 3
// 156.415 us; speedup vs baseline: 2.7257x; 1.0451x over previous
//
#include <hip/hip_runtime.h>
#include <math.h>

#define DD   256
#define BB   1024
#define NEGN 64
#define S1N  25
#define S2N  10
#define OUTN 128

struct Seg3 {
    const int* iself[3];
    const int* ineigh[3];
    float* out[3];
    int b0, b1;   // block counts of segment 0 and 1
};

struct SegF {
    const float* g0[3];
    const float* g1[3];
    float* out[3];
    int b0, b1;
};

// Fused: neigh-mean gather (FAN rows of feat) + self gather + SAGE layer0 (ReLU).
// 512 threads = 8 waves; wave w gathers row r0+w (R must be 8).
// Matmul: threads 0-255 -> rows 0-3, threads 256-511 -> rows 4-7.
template <int R, int FAN>
__global__ __launch_bounds__(512, 8)
void layer0_fused_k(const float* __restrict__ feat, Seg3 a,
                    const float* __restrict__ Ws, const float* __restrict__ Wn) {
    __shared__ float xsS[R][DD];
    __shared__ float xnS[R][DD];
    int blk = blockIdx.x;
    int seg, base;
    if (blk < a.b0) { seg = 0; base = 0; }
    else if (blk < a.b0 + a.b1) { seg = 1; base = a.b0; }
    else { seg = 2; base = a.b0 + a.b1; }
    const int* iself  = a.iself[seg];
    const int* ineigh = a.ineigh[seg];
    float* out = a.out[seg];
    int r0 = blk * R - base * R;

    int wv = threadIdx.x >> 6;   // 0..7 : one row per wave
    int c  = threadIdx.x & 63;

    {
        int row = r0 + wv;
        // wave-uniform indices -> SGPRs
        const int* ip = ineigh + (size_t)row * FAN;
        int myi = (c < FAN) ? ip[c] : 0;
        int selfi = __builtin_amdgcn_readfirstlane(iself[row]);
        // self row: one dwordx4 per lane, scalar base
        *(float4*)&xsS[wv][c * 4] =
            *(const float4*)(feat + (size_t)selfi * DD + c * 4);
        float4 a0 = make_float4(0.f, 0.f, 0.f, 0.f);
        float4 a1 = make_float4(0.f, 0.f, 0.f, 0.f);
#pragma unroll
        for (int s = 0; s < FAN; ++s) {
            int nr = __builtin_amdgcn_readlane(myi, s);
            float4 x = *(const float4*)(feat + (size_t)nr * DD + c * 4);
            if (s & 1) {
                a1.x += x.x; a1.y += x.y; a1.z += x.z; a1.w += x.w;
            } else {
                a0.x += x.x; a0.y += x.y; a0.z += x.z; a0.w += x.w;
            }
        }
        const float inv = 1.0f / FAN;
        a0.x = (a0.x + a1.x) * inv; a0.y = (a0.y + a1.y) * inv;
        a0.z = (a0.z + a1.z) * inv; a0.w = (a0.w + a1.w) * inv;
        *(float4*)&xnS[wv][c * 4] = a0;
    }
    __syncthreads();

    int tt = threadIdx.x & 255;
    int h  = tt >> 7;                    // 0: self/Ws, 1: neigh/Wn
    int j  = tt & 127;
    int rb = (threadIdx.x >> 8) * (R / 2);  // 0 or 4
    const float* Wj = (h ? Wn : Ws) + j;
    const float (*X)[DD] = h ? xnS : xsS;
    float acc[R / 2];
#pragma unroll
    for (int r = 0; r < R / 2; ++r) acc[r] = 0.f;
#pragma unroll 4
    for (int k4 = 0; k4 < DD; k4 += 4) {
        float w0 = Wj[(k4 + 0) * OUTN];
        float w1 = Wj[(k4 + 1) * OUTN];
        float w2 = Wj[(k4 + 2) * OUTN];
        float w3 = Wj[(k4 + 3) * OUTN];
#pragma unroll
        for (int r = 0; r < R / 2; ++r) {
            float4 x = *(const float4*)&X[rb + r][k4];
            acc[r] = fmaf(x.x, w0, acc[r]);
            acc[r] = fmaf(x.y, w1, acc[r]);
            acc[r] = fmaf(x.z, w2, acc[r]);
            acc[r] = fmaf(x.w, w3, acc[r]);
        }
    }
#pragma unroll
    for (int r = 0; r < R / 2; ++r) {
        int row = r0 + rb + r;
        out[(size_t)row * (2 * OUTN) + tt] = fmaxf(acc[r], 0.f);
    }
}

// Fused: neigh-mean over FAN consecutive g1 rows + final layer (no act) + L2 norm.
template <int R, int FAN>
__global__ __launch_bounds__(256)
void final_fused_k(SegF a, const float* __restrict__ Ws, const float* __restrict__ Wn) {
    __shared__ float xsS[R][DD];
    __shared__ float xnS[R][DD];
    __shared__ float nrmS[R];
    int blk = blockIdx.x;
    int seg, base;
    if (blk < a.b0) { seg = 0; base = 0; }
    else if (blk < a.b0 + a.b1) { seg = 1; base = a.b0; }
    else { seg = 2; base = a.b0 + a.b1; }
    const float* g0 = a.g0[seg];
    const float* g1 = a.g1[seg];
    float* out = a.out[seg];
    int r0 = (blk - base) * R;

    int wv = threadIdx.x >> 6;
    int c  = threadIdx.x & 63;

#pragma unroll
    for (int rr = 0; rr < R / 4; ++rr) {
        int r = wv * (R / 4) + rr;
        int row = r0 + r;
        *(float4*)&xsS[r][c * 4] = *(const float4*)(g0 + (size_t)row * DD + c * 4);
        float4 acc = make_float4(0.f, 0.f, 0.f, 0.f);
#pragma unroll
        for (int s = 0; s < FAN; ++s) {
            float4 x = *(const float4*)(g1 + ((size_t)row * FAN + s) * DD + c * 4);
            acc.x += x.x; acc.y += x.y; acc.z += x.z; acc.w += x.w;
        }
        const float inv = 1.0f / FAN;
        acc.x *= inv; acc.y *= inv; acc.z *= inv; acc.w *= inv;
        *(float4*)&xnS[r][c * 4] = acc;
    }
    __syncthreads();

    int j = threadIdx.x & (OUTN - 1);
    const float* Wj = ((threadIdx.x < OUTN) ? Ws : Wn) + j;
    const float (*X)[DD] = (threadIdx.x < OUTN) ? xsS : xnS;
    float acc[R];
#pragma unroll
    for (int r = 0; r < R; ++r) acc[r] = 0.f;
#pragma unroll 4
    for (int k4 = 0; k4 < DD; k4 += 4) {
        float w0 = Wj[(k4 + 0) * OUTN];
        float w1 = Wj[(k4 + 1) * OUTN];
        float w2 = Wj[(k4 + 2) * OUTN];
        float w3 = Wj[(k4 + 3) * OUTN];
#pragma unroll
        for (int r = 0; r < R; ++r) {
            float4 x = *(const float4*)&X[r][k4];
            acc[r] = fmaf(x.x, w0, acc[r]);
            acc[r] = fmaf(x.y, w1, acc[r]);
            acc[r] = fmaf(x.z, w2, acc[r]);
            acc[r] = fmaf(x.w, w3, acc[r]);
        }
    }
    __syncthreads();                 // done reading xsS; reuse as sq scratch
    float* sq = &xsS[0][0];
#pragma unroll
    for (int r = 0; r < R; ++r) sq[r * DD + threadIdx.x] = acc[r] * acc[r];
    __syncthreads();
    {
        int g = threadIdx.x >> 5, l = threadIdx.x & 31;
        float s = 0.f;
#pragma unroll
        for (int i = 0; i < 8; ++i) s += sq[g * DD + l + 32 * i];
        s += __shfl_down(s, 16, 64);
        s += __shfl_down(s, 8, 64);
        s += __shfl_down(s, 4, 64);
        s += __shfl_down(s, 2, 64);
        s += __shfl_down(s, 1, 64);
        if (l == 0) nrmS[g] = fmaxf(sqrtf(s), 1e-12f);
    }
    __syncthreads();
#pragma unroll
    for (int r = 0; r < R; ++r) {
        int row = r0 + r;
        out[(size_t)row * DD + threadIdx.x] = acc[r] / nrmS[r];
    }
}

__device__ __forceinline__ float softplus_f(float x) {
    return fmaxf(x, 0.f) + log1pf(expf(-fabsf(x)));
}

// per-b: aff[b], neg[b][0..63], and partial loss contribution part[b]
__global__ __launch_bounds__(256)
void aff_neg_k(const float* __restrict__ u1, const float* __restrict__ u2,
               const float* __restrict__ un, float* __restrict__ aff,
               float* __restrict__ neg, float* __restrict__ part) {
    __shared__ float u1s[DD];
    __shared__ float red[256];
    int b = blockIdx.x, t = threadIdx.x;
    float av = u1[(size_t)b * DD + t];
    u1s[t] = av;
    red[t] = av * u2[(size_t)b * DD + t];
    __syncthreads();
    for (int s = 128; s > 0; s >>= 1) { if (t < s) red[t] += red[t + s]; __syncthreads(); }
    float affv = red[0];
    __syncthreads();
    if (t == 0) aff[b] = affv;

    int j = t >> 2, q = t & 3;
    float acc = 0.f;
    const float* up = un + (size_t)j * DD + q * 64;
    const float* us = u1s + q * 64;
#pragma unroll
    for (int i = 0; i < 16; ++i) {
        float4 x = *(const float4*)(up + 4 * i);
        float4 y = *(const float4*)(us + 4 * i);
        acc = fmaf(x.x, y.x, acc); acc = fmaf(x.y, y.y, acc);
        acc = fmaf(x.z, y.z, acc); acc = fmaf(x.w, y.w, acc);
    }
    acc += __shfl_down(acc, 2, 64);
    acc += __shfl_down(acc, 1, 64);
    float sp = 0.f;
    if (q == 0) {
        neg[(size_t)b * NEGN + j] = acc;
        sp = softplus_f(acc);
    }
    if (t == 0) sp += softplus_f(-affv);
    red[t] = sp;
    __syncthreads();
    for (int s = 128; s > 0; s >>= 1) { if (t < s) red[t] += red[t + s]; __syncthreads(); }
    if (t == 0) part[b] = red[0];
}

__global__ __launch_bounds__(256)
void loss_final_k(const float* __restrict__ part, float* __restrict__ loss) {
    __shared__ float red[256];
    int t = threadIdx.x;
    red[t] = part[t] + part[t + 256] + part[t + 512] + part[t + 768];
    __syncthreads();
    for (int s = 128; s > 0; s >>= 1) { if (t < s) red[t] += red[t + s]; __syncthreads(); }
    if (t == 0) loss[0] = red[0] / (float)BB;
}

extern "C" void kernel_launch(void* const* d_in, const int* in_sizes, int n_in,
                              void* d_out, int out_size, void* d_ws, size_t ws_size,
                              hipStream_t stream) {
    const float* feat = (const float*)d_in[0];
    const float* Ws0  = (const float*)d_in[1];
    const float* Wn0  = (const float*)d_in[2];
    const float* Ws1  = (const float*)d_in[3];
    const float* Wn1  = (const float*)d_in[4];
    const int* s1_0 = (const int*)d_in[5];
    const int* s1_1 = (const int*)d_in[6];
    const int* s1_2 = (const int*)d_in[7];
    const int* s2_0 = (const int*)d_in[8];
    const int* s2_1 = (const int*)d_in[9];
    const int* s2_2 = (const int*)d_in[10];
    const int* n_0  = (const int*)d_in[11];
    const int* n_1  = (const int*)d_in[12];
    const int* n_2  = (const int*)d_in[13];

    float* out  = (float*)d_out;
    float* loss = out;                      // [1]
    float* aff  = out + 1;                  // [BB]
    float* neg  = out + 1 + BB;             // [BB*NEGN]
    float* u1   = out + 1 + BB + BB * NEGN; // [BB*DD]

    float* ws = (float*)d_ws;
    size_t off = 0;
    float* g1a = ws + off; off += (size_t)BB * S2N * DD;    // 10240 rows
    float* g1b = ws + off; off += (size_t)BB * S2N * DD;
    float* g1n = ws + off; off += (size_t)NEGN * S2N * DD;  // 640 rows
    float* g0a = ws + off; off += (size_t)BB * DD;
    float* g0b = ws + off; off += (size_t)BB * DD;
    float* g0n = ws + off; off += (size_t)NEGN * DD;
    float* u2  = ws + off; off += (size_t)BB * DD;
    float* un  = ws + off; off += (size_t)NEGN * DD;
    float* part = ws + off; off += BB;

    constexpr int R = 8;

    // Stage 1: layer0 on hop-1 rows (self=i1, neigh=mean of 25 hop-2 feats)
    {
        Seg3 a;
        a.iself[0] = s1_1; a.iself[1] = s2_1; a.iself[2] = n_1;
        a.ineigh[0] = s1_2; a.ineigh[1] = s2_2; a.ineigh[2] = n_2;
        a.out[0] = g1a; a.out[1] = g1b; a.out[2] = g1n;
        a.b0 = (BB * S2N) / R; a.b1 = (BB * S2N) / R;
        int nb = a.b0 + a.b1 + (NEGN * S2N) / R;
        layer0_fused_k<R, S1N><<<nb, 512, 0, stream>>>(feat, a, Ws0, Wn0);
    }
    // Stage 2: layer0 on hop-0 rows (self=i0, neigh=mean of 10 hop-1 feats)
    {
        Seg3 a;
        a.iself[0] = s1_0; a.iself[1] = s2_0; a.iself[2] = n_0;
        a.ineigh[0] = s1_1; a.ineigh[1] = s2_1; a.ineigh[2] = n_1;
        a.out[0] = g0a; a.out[1] = g0b; a.out[2] = g0n;
        a.b0 = BB / R; a.b1 = BB / R;
        int nb = a.b0 + a.b1 + NEGN / R;
        layer0_fused_k<R, S2N><<<nb, 512, 0, stream>>>(feat, a, Ws0, Wn0);
    }
    // Stage 3: final layer (self=g0, neigh=mean of 10 g1 rows) + L2 norm
    {
        SegF a;
        a.g0[0] = g0a; a.g0[1] = g0b; a.g0[2] = g0n;
        a.g1[0] = g1a; a.g1[1] = g1b; a.g1[2] = g1n;
        a.out[0] = u1; a.out[1] = u2; a.out[2] = un;
        a.b0 = BB / R; a.b1 = BB / R;
        int nb = a.b0 + a.b1 + NEGN / R;
        final_fused_k<R, S2N><<<nb, 256, 0, stream>>>(a, Ws1, Wn1);
    }

    aff_neg_k<<<BB, 256, 0, stream>>>(u1, u2, un, aff, neg, part);
    loss_final_k<<<1, 256, 0, stream>>>(part, loss);
}

// Round 4
// 154.964 us; speedup vs baseline: 2.7512x; 1.0094x over previous
//
#include <hip/hip_runtime.h>
#include <math.h>

#define DD   256
#define BB   1024
#define NEGN 64
#define S1N  25
#define S2N  10
#define OUTN 128

typedef unsigned int  uint;
typedef unsigned short ushort;
typedef short bf16x8 __attribute__((ext_vector_type(8)));
typedef float f32x4  __attribute__((ext_vector_type(4)));

__device__ __forceinline__ ushort f2bf(float x) {
    uint u = __float_as_uint(x);
    u += 0x7FFFu + ((u >> 16) & 1u);     // RNE
    return (ushort)(u >> 16);
}
__device__ __forceinline__ float bflo(uint v) { return __uint_as_float(v << 16); }
__device__ __forceinline__ float bfhi(uint v) { return __uint_as_float(v & 0xFFFF0000u); }

// ---- prep: Wt[col][k] = bf16(W_half[k][j]), col = h*128+j, [256][256] bf16 ----
__global__ __launch_bounds__(256)
void prep_w_k(const float* __restrict__ Ws0, const float* __restrict__ Wn0,
              ushort* __restrict__ Wt) {
    int col = blockIdx.x;     // 0..255
    int k   = threadIdx.x;    // 0..255
    const float* W = (col < OUTN) ? Ws0 : Wn0;
    int j = col & (OUTN - 1);
    Wt[(size_t)col * 256 + k] = f2bf(W[(size_t)k * OUTN + j]);
}

// ---- transform: ys[n] = feat[n]@Ws0, yn[n] = feat[n]@Wn0, bf16 out ----
// 256 thr = 4 waves; wave w owns output cols [64w,64w+64); 5 row-tiles of 16.
__global__ __launch_bounds__(256)
void transform_k(const float* __restrict__ feat, const ushort* __restrict__ Wt,
                 ushort* __restrict__ ys, ushort* __restrict__ yn) {
    __shared__ ushort As[16 * 256];
    int w = threadIdx.x >> 6, l = threadIdx.x & 63;
    int lane16 = l & 15, kb = (l >> 4) * 8;

    // B fragments: held in registers for the whole kernel
    bf16x8 bfr[4][8];
#pragma unroll
    for (int c = 0; c < 4; ++c) {
        int col = w * 64 + c * 16 + lane16;
#pragma unroll
        for (int kk = 0; kk < 8; ++kk)
            bfr[c][kk] = *(const bf16x8*)(Wt + (size_t)col * 256 + kk * 32 + kb);
    }

    int r  = threadIdx.x >> 4;   // A-load role: row 0..15
    int cq = threadIdx.x & 15;   // col-chunk 0..15 (16 cols each)

    for (int tile = 0; tile < 5; ++tile) {
        size_t row0 = (size_t)blockIdx.x * 80 + tile * 16;
        // load 16x256 f32 A, convert to bf16
        uint2 wr[4];
#pragma unroll
        for (int q = 0; q < 4; ++q) {
            float4 x = *(const float4*)(feat + (row0 + r) * 256 + cq * 16 + q * 4);
            wr[q].x = (uint)f2bf(x.x) | ((uint)f2bf(x.y) << 16);
            wr[q].y = (uint)f2bf(x.z) | ((uint)f2bf(x.w) << 16);
        }
        __syncthreads();   // previous tile's reads done
#pragma unroll
        for (int q = 0; q < 4; ++q) {
            int col = cq * 16 + q * 4;
            *(uint2*)&As[r * 256 + (col ^ ((r & 7) << 3))] = wr[q];
        }
        __syncthreads();

        f32x4 acc[4];
#pragma unroll
        for (int c = 0; c < 4; ++c)
#pragma unroll
            for (int j = 0; j < 4; ++j) acc[c][j] = 0.f;

#pragma unroll
        for (int kk = 0; kk < 8; ++kk) {
            int k0 = kk * 32 + kb;
            bf16x8 af = *(const bf16x8*)&As[lane16 * 256 + (k0 ^ ((lane16 & 7) << 3))];
#pragma unroll
            for (int c = 0; c < 4; ++c)
                acc[c] = __builtin_amdgcn_mfma_f32_16x16x32_bf16(af, bfr[c][kk], acc[c], 0, 0, 0);
        }

        ushort* dst = (w < 2) ? ys : yn;
        int cbase = (w & 1) * 64;
#pragma unroll
        for (int c = 0; c < 4; ++c) {
            int col = cbase + c * 16 + lane16;
#pragma unroll
            for (int j = 0; j < 4; ++j) {
                size_t grow = row0 + (l >> 4) * 4 + j;
                dst[grow * 128 + col] = f2bf(acc[c][j]);
            }
        }
    }
}

struct SegG {
    const int* iself[3];
    const int* ineigh[3];
    float* out[3];
    int b0, b1;
};

// ---- gather+mean+relu from transformed bf16 ys/yn: out[row] = relu([ys[iself] | mean yn]) ----
// 256 thr = 4 waves, 1 row per wave.
template <int FAN>
__global__ __launch_bounds__(256)
void gather_relu_k(const ushort* __restrict__ ysv, const ushort* __restrict__ ynv, SegG a) {
    int blk = blockIdx.x;
    int seg, base;
    if (blk < a.b0) { seg = 0; base = 0; }
    else if (blk < a.b0 + a.b1) { seg = 1; base = a.b0; }
    else { seg = 2; base = a.b0 + a.b1; }
    const int* isp = a.iself[seg];
    const int* inp = a.ineigh[seg];
    float* out = a.out[seg];

    int wv = threadIdx.x >> 6, c = threadIdx.x & 63;
    int row = (blk - base) * 4 + wv;

    const uint* ysp = (const uint*)ysv;
    const uint* ynp = (const uint*)ynv;

    int si = __builtin_amdgcn_readfirstlane(isp[row]);
    uint sv = ysp[(size_t)si * 64 + c];
    int myi = (c < FAN) ? inp[(size_t)row * FAN + c] : 0;

    float a0 = 0.f, a1 = 0.f;
#pragma unroll
    for (int s = 0; s < FAN; ++s) {
        int ni = __builtin_amdgcn_readlane(myi, s);
        uint v = ynp[(size_t)ni * 64 + c];
        a0 += bflo(v);
        a1 += bfhi(v);
    }
    const float inv = 1.0f / FAN;
    float2 sp, np_;
    sp.x = fmaxf(bflo(sv), 0.f);
    sp.y = fmaxf(bfhi(sv), 0.f);
    np_.x = fmaxf(a0 * inv, 0.f);
    np_.y = fmaxf(a1 * inv, 0.f);
    *(float2*)(out + (size_t)row * 256 + 2 * c) = sp;
    *(float2*)(out + (size_t)row * 256 + 128 + 2 * c) = np_;
}

struct SegF {
    const float* g0[3];
    const float* g1[3];
    float* out[3];
    int b0, b1;
};

// ---- final layer: mean over FAN g1 rows + [g0|mg1]@W1 + L2 norm ----
template <int R, int FAN>
__global__ __launch_bounds__(256)
void final_fused_k(SegF a, const float* __restrict__ Ws, const float* __restrict__ Wn) {
    __shared__ float xsS[R][DD];
    __shared__ float xnS[R][DD];
    __shared__ float nrmS[R];
    int blk = blockIdx.x;
    int seg, base;
    if (blk < a.b0) { seg = 0; base = 0; }
    else if (blk < a.b0 + a.b1) { seg = 1; base = a.b0; }
    else { seg = 2; base = a.b0 + a.b1; }
    const float* g0 = a.g0[seg];
    const float* g1 = a.g1[seg];
    float* out = a.out[seg];
    int r0 = (blk - base) * R;

    int wv = threadIdx.x >> 6;
    int c  = threadIdx.x & 63;

#pragma unroll
    for (int rr = 0; rr < R / 4; ++rr) {
        int r = wv * (R / 4) + rr;
        int row = r0 + r;
        *(float4*)&xsS[r][c * 4] = *(const float4*)(g0 + (size_t)row * DD + c * 4);
        float4 acc = make_float4(0.f, 0.f, 0.f, 0.f);
#pragma unroll
        for (int s = 0; s < FAN; ++s) {
            float4 x = *(const float4*)(g1 + ((size_t)row * FAN + s) * DD + c * 4);
            acc.x += x.x; acc.y += x.y; acc.z += x.z; acc.w += x.w;
        }
        const float inv = 1.0f / FAN;
        acc.x *= inv; acc.y *= inv; acc.z *= inv; acc.w *= inv;
        *(float4*)&xnS[r][c * 4] = acc;
    }
    __syncthreads();

    int j = threadIdx.x & (OUTN - 1);
    const float* Wj = ((threadIdx.x < OUTN) ? Ws : Wn) + j;
    const float (*X)[DD] = (threadIdx.x < OUTN) ? xsS : xnS;
    float acc[R];
#pragma unroll
    for (int r = 0; r < R; ++r) acc[r] = 0.f;
#pragma unroll 4
    for (int k4 = 0; k4 < DD; k4 += 4) {
        float w0 = Wj[(k4 + 0) * OUTN];
        float w1 = Wj[(k4 + 1) * OUTN];
        float w2 = Wj[(k4 + 2) * OUTN];
        float w3 = Wj[(k4 + 3) * OUTN];
#pragma unroll
        for (int r = 0; r < R; ++r) {
            float4 x = *(const float4*)&X[r][k4];
            acc[r] = fmaf(x.x, w0, acc[r]);
            acc[r] = fmaf(x.y, w1, acc[r]);
            acc[r] = fmaf(x.z, w2, acc[r]);
            acc[r] = fmaf(x.w, w3, acc[r]);
        }
    }
    __syncthreads();
    float* sq = &xsS[0][0];
#pragma unroll
    for (int r = 0; r < R; ++r) sq[r * DD + threadIdx.x] = acc[r] * acc[r];
    __syncthreads();
    {
        int g = threadIdx.x >> 5, l = threadIdx.x & 31;
        float s = 0.f;
#pragma unroll
        for (int i = 0; i < 8; ++i) s += sq[g * DD + l + 32 * i];
        s += __shfl_down(s, 16, 64);
        s += __shfl_down(s, 8, 64);
        s += __shfl_down(s, 4, 64);
        s += __shfl_down(s, 2, 64);
        s += __shfl_down(s, 1, 64);
        if (l == 0) nrmS[g] = fmaxf(sqrtf(s), 1e-12f);
    }
    __syncthreads();
#pragma unroll
    for (int r = 0; r < R; ++r) {
        int row = r0 + r;
        out[(size_t)row * DD + threadIdx.x] = acc[r] / nrmS[r];
    }
}

__device__ __forceinline__ float softplus_f(float x) {
    return fmaxf(x, 0.f) + log1pf(expf(-fabsf(x)));
}

__global__ __launch_bounds__(256)
void aff_neg_k(const float* __restrict__ u1, const float* __restrict__ u2,
               const float* __restrict__ un, float* __restrict__ aff,
               float* __restrict__ neg, float* __restrict__ part) {
    __shared__ float u1s[DD];
    __shared__ float red[256];
    int b = blockIdx.x, t = threadIdx.x;
    float av = u1[(size_t)b * DD + t];
    u1s[t] = av;
    red[t] = av * u2[(size_t)b * DD + t];
    __syncthreads();
    for (int s = 128; s > 0; s >>= 1) { if (t < s) red[t] += red[t + s]; __syncthreads(); }
    float affv = red[0];
    __syncthreads();
    if (t == 0) aff[b] = affv;

    int j = t >> 2, q = t & 3;
    float acc = 0.f;
    const float* up = un + (size_t)j * DD + q * 64;
    const float* us = u1s + q * 64;
#pragma unroll
    for (int i = 0; i < 16; ++i) {
        float4 x = *(const float4*)(up + 4 * i);
        float4 y = *(const float4*)(us + 4 * i);
        acc = fmaf(x.x, y.x, acc); acc = fmaf(x.y, y.y, acc);
        acc = fmaf(x.z, y.z, acc); acc = fmaf(x.w, y.w, acc);
    }
    acc += __shfl_down(acc, 2, 64);
    acc += __shfl_down(acc, 1, 64);
    float sp = 0.f;
    if (q == 0) {
        neg[(size_t)b * NEGN + j] = acc;
        sp = softplus_f(acc);
    }
    if (t == 0) sp += softplus_f(-affv);
    red[t] = sp;
    __syncthreads();
    for (int s = 128; s > 0; s >>= 1) { if (t < s) red[t] += red[t + s]; __syncthreads(); }
    if (t == 0) part[b] = red[0];
}

__global__ __launch_bounds__(256)
void loss_final_k(const float* __restrict__ part, float* __restrict__ loss) {
    __shared__ float red[256];
    int t = threadIdx.x;
    red[t] = part[t] + part[t + 256] + part[t + 512] + part[t + 768];
    __syncthreads();
    for (int s = 128; s > 0; s >>= 1) { if (t < s) red[t] += red[t + s]; __syncthreads(); }
    if (t == 0) loss[0] = red[0] / (float)BB;
}

extern "C" void kernel_launch(void* const* d_in, const int* in_sizes, int n_in,
                              void* d_out, int out_size, void* d_ws, size_t ws_size,
                              hipStream_t stream) {
    const float* feat = (const float*)d_in[0];
    const float* Ws0  = (const float*)d_in[1];
    const float* Wn0  = (const float*)d_in[2];
    const float* Ws1  = (const float*)d_in[3];
    const float* Wn1  = (const float*)d_in[4];
    const int* s1_0 = (const int*)d_in[5];
    const int* s1_1 = (const int*)d_in[6];
    const int* s1_2 = (const int*)d_in[7];
    const int* s2_0 = (const int*)d_in[8];
    const int* s2_1 = (const int*)d_in[9];
    const int* s2_2 = (const int*)d_in[10];
    const int* n_0  = (const int*)d_in[11];
    const int* n_1  = (const int*)d_in[12];
    const int* n_2  = (const int*)d_in[13];

    float* out  = (float*)d_out;
    float* loss = out;
    float* aff  = out + 1;
    float* neg  = out + 1 + BB;
    float* u1   = out + 1 + BB + BB * NEGN;

    char* wsb = (char*)d_ws;
    size_t off = 0;
    ushort* Wt = (ushort*)(wsb + off); off += (size_t)256 * 256 * 2;        // 128KB
    ushort* ys = (ushort*)(wsb + off); off += (size_t)200000 * 128 * 2;     // 51.2MB
    ushort* yn = (ushort*)(wsb + off); off += (size_t)200000 * 128 * 2;     // 51.2MB
    float* g1a = (float*)(wsb + off); off += (size_t)BB * S2N * DD * 4;
    float* g1b = (float*)(wsb + off); off += (size_t)BB * S2N * DD * 4;
    float* g1n = (float*)(wsb + off); off += (size_t)NEGN * S2N * DD * 4;
    float* g0a = (float*)(wsb + off); off += (size_t)BB * DD * 4;
    float* g0b = (float*)(wsb + off); off += (size_t)BB * DD * 4;
    float* g0n = (float*)(wsb + off); off += (size_t)NEGN * DD * 4;
    float* u2  = (float*)(wsb + off); off += (size_t)BB * DD * 4;
    float* un  = (float*)(wsb + off); off += (size_t)NEGN * DD * 4;
    float* part = (float*)(wsb + off); off += (size_t)BB * 4;

    prep_w_k<<<256, 256, 0, stream>>>(Ws0, Wn0, Wt);
    transform_k<<<2500, 256, 0, stream>>>(feat, Wt, ys, yn);

    // stage 1: g1 rows (self=i1, neigh=mean of 25 yn[i2])
    {
        SegG a;
        a.iself[0] = s1_1; a.iself[1] = s2_1; a.iself[2] = n_1;
        a.ineigh[0] = s1_2; a.ineigh[1] = s2_2; a.ineigh[2] = n_2;
        a.out[0] = g1a; a.out[1] = g1b; a.out[2] = g1n;
        a.b0 = (BB * S2N) / 4; a.b1 = (BB * S2N) / 4;
        int nb = a.b0 + a.b1 + (NEGN * S2N) / 4;
        gather_relu_k<S1N><<<nb, 256, 0, stream>>>(ys, yn, a);
    }
    // stage 2: g0 rows (self=i0, neigh=mean of 10 yn[i1])
    {
        SegG a;
        a.iself[0] = s1_0; a.iself[1] = s2_0; a.iself[2] = n_0;
        a.ineigh[0] = s1_1; a.ineigh[1] = s2_1; a.ineigh[2] = n_1;
        a.out[0] = g0a; a.out[1] = g0b; a.out[2] = g0n;
        a.b0 = BB / 4; a.b1 = BB / 4;
        int nb = a.b0 + a.b1 + NEGN / 4;
        gather_relu_k<S2N><<<nb, 256, 0, stream>>>(ys, yn, a);
    }
    // stage 3: final layer + L2 norm
    {
        SegF a;
        a.g0[0] = g0a; a.g0[1] = g0b; a.g0[2] = g0n;
        a.g1[0] = g1a; a.g1[1] = g1b; a.g1[2] = g1n;
        a.out[0] = u1; a.out[1] = u2; a.out[2] = un;
        a.b0 = BB / 8; a.b1 = BB / 8;
        int nb = a.b0 + a.b1 + NEGN / 8;
        final_fused_k<8, S2N><<<nb, 256, 0, stream>>>(a, Ws1, Wn1);
    }

    aff_neg_k<<<BB, 256, 0, stream>>>(u1, u2, un, aff, neg, part);
    loss_final_k<<<1, 256, 0, stream>>>(part, loss);
}